// Round 10
// baseline (35.281 us; speedup 1.0000x reference)
//
#include <hip/hip_runtime.h>
#include <math.h>

// SMEFTNet forward. B=128, N=128, H=16.  TWO kernels.
// K1 "fused": 256 blocks (batch, ihalf) x 1024 thr (16 waves).
//   Phase 0: conv0 for ALL 128 nodes of the batch (duplicated across the
//   batch's two blocks; +25% conv0 work buys zero cross-block deps).
//   Outputs to LDS: u_lds/v_lds[128][20] (pad->2-way banks only), rec_lds
//   (rotated re,im + inv-norm). One __syncthreads.
//   Phase 1: conv1 for this block's 64-node half, j-data from LDS.
//   Phase 2: per-wave readout partials (xor16 swizzle + xor32 shfl), LDS
//   combine across 16 waves -> part[block][20] global.
// K2: 128 blocks x 64 thr: combine 2 partials, 16->32->32->1 MLP -> out.
// Math bodies identical to the verified R6 kernel (absmax 0.0).

#define BB 128
#define NN 128
#define BN (BB * NN)

typedef float f32x2 __attribute__((ext_vector_type(2)));

__device__ __forceinline__ f32x2 pk2(float s) { f32x2 r; r[0] = s; r[1] = s; return r; }
__device__ __forceinline__ f32x2 pkfma(f32x2 a, f32x2 b, f32x2 c) {
    return __builtin_elementwise_fma(a, b, c);
}
__device__ __forceinline__ f32x2 pkmax(f32x2 a, f32x2 b) {
    return __builtin_elementwise_max(a, b);
}

template <int CTRL>
__device__ __forceinline__ float dpp_add(float x) {
    int tmp = __builtin_amdgcn_update_dpp(0, __float_as_int(x), CTRL, 0xF, 0xF, true);
    return x + __int_as_float(tmp);
}

// Sum within each 16-lane row; result valid in lane (l|15) of each row.
__device__ __forceinline__ float grp16_sum(float x) {
    x = dpp_add<0xB1>(x);   // quad_perm [1,0,3,2]
    x = dpp_add<0x4E>(x);   // quad_perm [2,3,0,1]
    x = dpp_add<0x114>(x);  // row_shr:4
    x = dpp_add<0x118>(x);  // row_shr:8
    return x;
}

__device__ __forceinline__ float bcast_grp(float x, int bidx) {
    return __int_as_float(__builtin_amdgcn_ds_bpermute(bidx, __float_as_int(x)));
}

__device__ __forceinline__ f32x2 grp16_red2(f32x2 x, int bidx) {
    f32x2 r;
    r[0] = bcast_grp(grp16_sum(x[0]), bidx);
    r[1] = bcast_grp(grp16_sum(x[1]), bidx);
    return r;
}

// ---------------- K1: fused conv0 + conv1 + block partials ----------------
__global__ __launch_bounds__(1024, 4) void fused_kernel(
    const float* __restrict__ pt,    // (B,N)
    const float* __restrict__ ang,   // (B,N,2)
    const float* __restrict__ w0,    // c0_w0 (5,16)
    const float* __restrict__ b0,    // c0_b0 (16)
    const float* __restrict__ w1,    // c0_w1 (16,17)
    const float* __restrict__ b1,    // c0_b1 (17)
    const float* __restrict__ nw0,   // c1_w0 (50,16)
    const float* __restrict__ nb0,   // c1_b0 (16)
    const float* __restrict__ nw1,   // c1_w1 (16,17)
    const float* __restrict__ nb1,   // c1_b1 (17)
    float* __restrict__ part)        // (256,20)
{
    const int tid   = threadIdx.x;
    const int lane  = tid & 63;
    const int wid   = tid >> 6;        // 0..15
    const int t     = lane & 15;
    const int g     = lane >> 4;
    const int batch = blockIdx.x >> 1;
    const int ihalf = blockIdx.x & 1;
    const int nbase = batch * NN;

    __shared__ float u_lds[128][20];
    __shared__ float v_lds[128][20];
    __shared__ float4 rec_lds[128];
    __shared__ float hls[64][20];
    __shared__ float Ap2[16][20];

    // ---- phase 0: conv0 for all 128 nodes (2 rounds of 64) ----
    // j payloads in registers, shared by both rounds
    float2 ajv[8]; float abszj[8], ivjr[8];
    #pragma unroll
    for (int jj = 0; jj < 8; ++jj) {
        ajv[jj] = ((const float2*)ang)[nbase + jj * 16 + t];
        const float r2 = fmaf(ajv[jj].x, ajv[jj].x, ajv[jj].y * ajv[jj].y);
        abszj[jj] = __builtin_amdgcn_sqrtf(r2);
        ivjr[jj]  = __builtin_amdgcn_rsqf(r2);
    }
    // layer-0 constants (uniform addresses -> scalar loads)
    f32x2 q02[8], wc2[8], ws2[8], wac2[8], bb2[8];
    #pragma unroll
    for (int p = 0; p < 8; ++p) {
        f32x2 wa  = *(const f32x2*)(w0 + 2 * p);
        f32x2 wb  = *(const f32x2*)(w0 + 16 + 2 * p);
        f32x2 wcv = *(const f32x2*)(w0 + 32 + 2 * p);
        bb2[p]  = *(const f32x2*)(b0 + 2 * p);
        wac2[p] = wa - wcv;                      // Wa-Wc
        q02[p]  = wb + wcv;                      // Wb+Wc
        wc2[p]  = *(const f32x2*)(w0 + 48 + 2 * p);
        ws2[p]  = *(const f32x2*)(w0 + 64 + 2 * p);
    }

    const int o = lane & 31;
    const int kk = o & 15;
    const bool isU = (o < 16);
    const int bidx = (lane | 15) << 2;

    #pragma unroll
    for (int r = 0; r < 2; ++r) {
        const int nlr    = wid * 4 + g;          // round-local node [0,64)
        const int nlocal = r * 64 + nlr;
        const int ni     = nbase + nlocal;

        const float2 ai = ((const float2*)ang)[ni];
        const float r2i = fmaf(ai.x, ai.x, ai.y * ai.y);
        const float abszi = __builtin_amdgcn_sqrtf(r2i);
        const float invi  = __builtin_amdgcn_rsqf(r2i);

        f32x2 u0b2[8];
        #pragma unroll
        for (int p = 0; p < 8; ++p) u0b2[p] = pkfma(pk2(abszi), wac2[p], bb2[p]);

        f32x2 A2[8];
        #pragma unroll
        for (int p = 0; p < 8; ++p) A2[p] = pk2(0.0f);
        float degf = 0.0f;

        #pragma unroll
        for (int jj = 0; jj < 8; ++jj) {
            const float2 aj = ajv[jj];
            const float dre = ai.x - aj.x, dim = ai.y - aj.y;
            const float d2 = fmaf(dre, dre, dim * dim);
            const float adjf = (d2 <= 0.16f) ? 1.0f : 0.0f;
            degf += adjf;
            const float inv = fminf(invi * ivjr[jj], 1e12f);
            const f32x2 cos2 = pk2(fmaf(ai.x, aj.x, ai.y * aj.y) * inv);
            const f32x2 sin2 = pk2(fmaf(ai.y, aj.x, -(ai.x * aj.y)) * inv);
            const f32x2 ab2 = pk2(abszj[jj]);
            const f32x2 adj2 = pk2(adjf);
            #pragma unroll
            for (int p = 0; p < 8; ++p) {
                f32x2 z = pkfma(ab2, q02[p], u0b2[p]);
                z = pkfma(cos2, wc2[p], z);
                z = pkfma(sin2, ws2[p], z);
                f32x2 a = pkmax(z, z * 0.01f);
                A2[p] = pkfma(a, adj2, A2[p]);
            }
        }

        f32x2 Ak2[8];
        #pragma unroll
        for (int p = 0; p < 8; ++p) Ak2[p] = grp16_red2(A2[p], bidx);
        const float invdeg = __builtin_amdgcn_rcpf(bcast_grp(grp16_sum(degf), bidx));

        // 2nd MLP layer (epilogue loads: channel t + gamma column)
        f32x2 s2 = pk2(0.0f), g2 = pk2(0.0f);
        #pragma unroll
        for (int p = 0; p < 8; ++p) {
            f32x2 wr; wr[0] = w1[(2 * p) * 17 + t];  wr[1] = w1[(2 * p + 1) * 17 + t];
            f32x2 wg; wg[0] = w1[(2 * p) * 17 + 16]; wg[1] = w1[(2 * p + 1) * 17 + 16];
            s2 = pkfma(Ak2[p], wr, s2);
            g2 = pkfma(Ak2[p], wg, g2);
        }
        const float mt    = fmaf(s2[0] + s2[1], invdeg, b1[t]);
        const float gamma = fmaf(g2[0] + g2[1], invdeg, b1[16]);

        // rotation (v_cos/v_sin take revolutions); norm preserved -> store invi
        {
            const float gf = gamma - floorf(gamma);
            const float cs = __builtin_amdgcn_cosf(gf);
            const float sn = __builtin_amdgcn_sinf(gf);
            if (t == 0) {
                const float re2 = cs * ai.x - sn * ai.y;
                const float im2 = fmaf(sn, ai.x, cs * ai.y);
                rec_lds[nlocal] = make_float4(re2, im2, invi, 0.0f);
            }
        }

        hls[nlr][t] = mt;   // same-wave exchange (in-order, no barrier)

        // proj for conv1: combined weights per output o (reloaded per round)
        float wkp[16];
        {
            const int off = isU ? 0 : 256;
            #pragma unroll
            for (int c = 0; c < 16; ++c) {
                const float a_ = nw0[off + c * 16 + kk];
                const float c_ = nw0[512 + c * 16 + kk];
                wkp[c] = isU ? (a_ - c_) : (a_ + c_);
            }
        }
        const float accb = isU ? nb0[kk] : 0.0f;
        #pragma unroll
        for (int ps = 0; ps < 2; ++ps) {
            const int nl = (lane >> 5) + 2 * ps;
            const int node = wid * 4 + nl;       // round-local
            float acc = accb;
            #pragma unroll
            for (int c = 0; c < 16; ++c) acc = fmaf(hls[node][c], wkp[c], acc);
            if (isU) u_lds[r * 64 + node][kk] = acc;
            else     v_lds[r * 64 + node][kk] = acc;
        }
    }
    __syncthreads();

    // ---- phase 1: conv1 for this block's 64-node half ----
    const int nlocal1 = ihalf * 64 + wid * 4 + g;
    const int ni1 = nbase + nlocal1;
    const float4 a4 = rec_lds[nlocal1];
    const float rei = a4.x, imi = a4.y, invi1 = a4.z;
    const float ptf = pt[ni1];

    f32x2 u0b2[8];
    {
        const float4* ug = (const float4*)&u_lds[nlocal1][0];
        float4 q0 = ug[0], q1 = ug[1], q2 = ug[2], q3 = ug[3];
        u0b2[0][0] = q0.x; u0b2[0][1] = q0.y; u0b2[1][0] = q0.z; u0b2[1][1] = q0.w;
        u0b2[2][0] = q1.x; u0b2[2][1] = q1.y; u0b2[3][0] = q1.z; u0b2[3][1] = q1.w;
        u0b2[4][0] = q2.x; u0b2[4][1] = q2.y; u0b2[5][0] = q2.z; u0b2[5][1] = q2.w;
        u0b2[6][0] = q3.x; u0b2[6][1] = q3.y; u0b2[7][0] = q3.z; u0b2[7][1] = q3.w;
    }
    f32x2 wc1[8], ws1[8];   // uniform -> scalar loads
    #pragma unroll
    for (int p = 0; p < 8; ++p) {
        wc1[p] = *(const f32x2*)(nw0 + 768 + 2 * p);
        ws1[p] = *(const f32x2*)(nw0 + 784 + 2 * p);
    }

    f32x2 A2[8];
    #pragma unroll
    for (int p = 0; p < 8; ++p) A2[p] = pk2(0.0f);
    float degf = 0.0f;

    #pragma unroll 4
    for (int jj = 0; jj < 8; ++jj) {
        const int j = jj * 16 + t;
        const float4 rj = rec_lds[j];
        f32x2 vj2[8];
        {
            const float4* vg = (const float4*)&v_lds[j][0];
            float4 q0 = vg[0], q1 = vg[1], q2 = vg[2], q3 = vg[3];
            vj2[0][0] = q0.x; vj2[0][1] = q0.y; vj2[1][0] = q0.z; vj2[1][1] = q0.w;
            vj2[2][0] = q1.x; vj2[2][1] = q1.y; vj2[3][0] = q1.z; vj2[3][1] = q1.w;
            vj2[4][0] = q2.x; vj2[4][1] = q2.y; vj2[5][0] = q2.z; vj2[5][1] = q2.w;
            vj2[6][0] = q3.x; vj2[6][1] = q3.y; vj2[7][0] = q3.z; vj2[7][1] = q3.w;
        }
        const float dre = rei - rj.x, dim = imi - rj.y;
        const float d2 = fmaf(dre, dre, dim * dim);
        const float adjf = (d2 <= 0.16f) ? 1.0f : 0.0f;
        degf += adjf;
        const float inv = fminf(invi1 * rj.z, 1e12f);
        const f32x2 cos2 = pk2(fmaf(rei, rj.x, imi * rj.y) * inv);
        const f32x2 sin2 = pk2(fmaf(imi, rj.x, -(rei * rj.y)) * inv);
        const f32x2 adj2 = pk2(adjf);
        #pragma unroll
        for (int p = 0; p < 8; ++p) {
            f32x2 z = u0b2[p] + vj2[p];
            z = pkfma(cos2, wc1[p], z);
            z = pkfma(sin2, ws1[p], z);
            f32x2 a = pkmax(z, z * 0.01f);
            A2[p] = pkfma(a, adj2, A2[p]);
        }
    }

    f32x2 Ak2[8];
    #pragma unroll
    for (int p = 0; p < 8; ++p) Ak2[p] = grp16_red2(A2[p], bidx);
    const float invdeg = __builtin_amdgcn_rcpf(bcast_grp(grp16_sum(degf), bidx));

    f32x2 s2 = pk2(0.0f), g2 = pk2(0.0f);
    #pragma unroll
    for (int p = 0; p < 8; ++p) {
        f32x2 wr; wr[0] = nw1[(2 * p) * 17 + t];  wr[1] = nw1[(2 * p + 1) * 17 + t];
        f32x2 wg; wg[0] = nw1[(2 * p) * 17 + 16]; wg[1] = nw1[(2 * p + 1) * 17 + 16];
        s2 = pkfma(Ak2[p], wr, s2);
        g2 = pkfma(Ak2[p], wg, g2);
    }
    const float mt    = fmaf(s2[0] + s2[1], invdeg, nb1[t]);
    const float gamma = fmaf(g2[0] + g2[1], invdeg, nb1[16]);

    const float gf = gamma - floorf(gamma);
    const float cs = __builtin_amdgcn_cosf(gf);
    const float sn = __builtin_amdgcn_sinf(gf);
    const float re2 = cs * rei - sn * imi;
    const float im2 = fmaf(sn, rei, cs * imi);

    // ---- phase 2: readout partials ----
    float pm  = ptf * mt;
    float pre = ptf * re2;
    float pim = ptf * im2;
    float ppt = ptf;
    pm  += __int_as_float(__builtin_amdgcn_ds_swizzle(__float_as_int(pm),  0x401F));
    pre += __int_as_float(__builtin_amdgcn_ds_swizzle(__float_as_int(pre), 0x401F));
    pim += __int_as_float(__builtin_amdgcn_ds_swizzle(__float_as_int(pim), 0x401F));
    ppt += __int_as_float(__builtin_amdgcn_ds_swizzle(__float_as_int(ppt), 0x401F));
    pm  += __shfl_xor(pm, 32);
    pre += __shfl_xor(pre, 32);
    pim += __shfl_xor(pim, 32);
    ppt += __shfl_xor(ppt, 32);

    if (lane < 16)       Ap2[wid][lane] = pm;
    else if (lane == 16) Ap2[wid][16] = pre;
    else if (lane == 17) Ap2[wid][17] = pim;
    else if (lane == 18) Ap2[wid][18] = ppt;
    __syncthreads();

    if (wid == 0 && lane < 19) {
        float s0 = 0.0f, s1 = 0.0f, s2_ = 0.0f, s3 = 0.0f;
        #pragma unroll
        for (int w = 0; w < 16; w += 4) {
            s0 += Ap2[w + 0][lane];
            s1 += Ap2[w + 1][lane];
            s2_ += Ap2[w + 2][lane];
            s3 += Ap2[w + 3][lane];
        }
        part[(size_t)blockIdx.x * 20 + lane] = (s0 + s1) + (s2_ + s3);
    }
}

// ---------------- K2: final readout (1 wave per batch) ----------------
__global__ __launch_bounds__(64) void readout_kernel(
    const float* __restrict__ part,  // (256,20)
    const float* __restrict__ w0, const float* __restrict__ b0,  // (16,32),(32)
    const float* __restrict__ w1, const float* __restrict__ b1,  // (32,32),(32)
    const float* __restrict__ w2, const float* __restrict__ b2,  // (32,1),(1)
    float* __restrict__ out) {
    const int b = blockIdx.x;
    const int t = threadIdx.x;

    __shared__ float sb[19];
    __shared__ float xg[18];
    __shared__ float h1r[32];

    if (t < 19) sb[t] = part[(size_t)(2 * b) * 20 + t] + part[(size_t)(2 * b) * 20 + 20 + t];
    // 64 threads = one wave: LDS ops are in-order, no barrier needed
    const float invd = __builtin_amdgcn_rcpf(sb[18]);
    if (t < 18) xg[t] = sb[t] * invd;

    if (t < 32) {
        float h = b0[t];
        #pragma unroll
        for (int k = 0; k < 16; ++k) h = fmaf(xg[k], w0[k * 32 + t], h);
        h = fmaxf(h, 0.01f * h);
        h1r[t] = h;
    }
    if (t < 32) {
        float h = b1[t];
        #pragma unroll
        for (int k = 0; k < 32; ++k) h = fmaf(h1r[k], w1[k * 32 + t], h);
        h = fmaxf(h, 0.01f * h);
        float p = h * w2[t];
        #pragma unroll
        for (int off = 16; off; off >>= 1) p += __shfl_xor(p, off);
        if (t == 0) {
            out[b * 3 + 0] = 1.0f / (1.0f + expf(-(p + b2[0])));
            out[b * 3 + 1] = xg[16];
            out[b * 3 + 2] = xg[17];
        }
    }
}

extern "C" void kernel_launch(void* const* d_in, const int* in_sizes, int n_in,
                              void* d_out, int out_size, void* d_ws, size_t ws_size,
                              hipStream_t stream) {
    const float* pt    = (const float*)d_in[0];
    const float* ang   = (const float*)d_in[1];
    const float* c0_w0 = (const float*)d_in[2];
    const float* c0_b0 = (const float*)d_in[3];
    const float* c0_w1 = (const float*)d_in[4];
    const float* c0_b1 = (const float*)d_in[5];
    const float* c1_w0 = (const float*)d_in[6];
    const float* c1_b0 = (const float*)d_in[7];
    const float* c1_w1 = (const float*)d_in[8];
    const float* c1_b1 = (const float*)d_in[9];
    const float* r_w0  = (const float*)d_in[10];
    const float* r_b0  = (const float*)d_in[11];
    const float* r_w1  = (const float*)d_in[12];
    const float* r_b1  = (const float*)d_in[13];
    const float* r_w2  = (const float*)d_in[14];
    const float* r_b2  = (const float*)d_in[15];
    float* out = (float*)d_out;
    float* partb = (float*)d_ws;               // 256*20 floats

    hipLaunchKernelGGL(fused_kernel, dim3(2 * BB), dim3(1024), 0, stream,
                       pt, ang, c0_w0, c0_b0, c0_w1, c0_b1,
                       c1_w0, c1_b0, c1_w1, c1_b1, partb);
    hipLaunchKernelGGL(readout_kernel, dim3(BB), dim3(64), 0, stream,
                       partb, r_w0, r_b0, r_w1, r_b1, r_w2, r_b2, out);
}